// Round 4
// baseline (357.798 us; speedup 1.0000x reference)
//
#include <hip/hip_runtime.h>
#include <math.h>

// B=8, S=512, D=1024, P=128, H=8 ; rows = B*S = 4096
typedef __attribute__((ext_vector_type(8))) short bf16x8_t;
typedef __attribute__((ext_vector_type(4))) float f32x4_t;

__device__ __forceinline__ float sigmoidf_(float x){ return 1.f/(1.f+expf(-x)); }
__device__ __forceinline__ float geluf_(float x){ return 0.5f*x*(1.f+erff(x*0.70710678118654752f)); }
__device__ __forceinline__ unsigned short f2bf(float x){
  unsigned int u = __float_as_uint(x);
  return (unsigned short)((u + 0x7fffu + ((u>>16)&1u)) >> 16);
}
__device__ __forceinline__ float bf2f(unsigned short h){
  return __uint_as_float(((unsigned int)h)<<16);
}
__device__ __forceinline__ bf16x8_t ldfrag(const unsigned short* p){
  union { bf16x8_t v; uint2 q[2]; } u;
  u.q[0] = *(const uint2*)p; u.q[1] = *(const uint2*)(p+4); return u.v;
}
__device__ __forceinline__ bf16x8_t ldfrag16(const unsigned short* p){
  union { bf16x8_t v; uint4 q; } u; u.q = *(const uint4*)p; return u.v;
}

// ---------- bias concat ----------
__global__ __launch_bounds__(256) void bias_pack(const float* __restrict__ ba,
    const float* __restrict__ bp, float* __restrict__ bcat){
  int t = threadIdx.x; bcat[t] = (t<128)? ba[t] : bp[t-128];
}

// ---------- transpose + split fp32 -> (hi,lo) bf16 ; dst[c][r] = src[r][c] ----------
__global__ __launch_bounds__(256) void transpose_split(
    const float* __restrict__ src, unsigned short* __restrict__ dhi,
    unsigned short* __restrict__ dlo, int R, int C)
{
  long zoff = (long)blockIdx.z * R * C;
  src += zoff; dhi += zoff; dlo += zoff;
  __shared__ float tile[32][33];
  int c0 = blockIdx.x*32, r0 = blockIdx.y*32;
  int j = threadIdx.x & 31, i0 = threadIdx.x >> 5;
  #pragma unroll
  for (int ii=0; ii<4; ++ii){ int i = i0 + ii*8;
    tile[i][j] = src[(long)(r0+i)*C + c0 + j]; }
  __syncthreads();
  #pragma unroll
  for (int ii=0; ii<4; ++ii){ int i = i0 + ii*8;
    float v = tile[j][i];
    unsigned short h = f2bf(v);
    dhi[(long)(c0+i)*R + r0 + j] = h;
    dlo[(long)(c0+i)*R + r0 + j] = f2bf(v - bf2f(h));
  }
}

// ---------- split-bf16 MFMA GEMM, fp32 A split on the fly (E-gemm only) ----------
template<int EPI>
__global__ __launch_bounds__(256) void gemm_mfma(
    const float* __restrict__ A, const unsigned short* __restrict__ Bhi,
    const unsigned short* __restrict__ Blo,
    const float* __restrict__ bias, const float* __restrict__ resid,
    float* __restrict__ C, int M, int N, int K,
    long sA, long sB, long sBias, long sC)
{
  int z = blockIdx.z;
  A += z*sA; Bhi += z*sB; Blo += z*sB; bias += z*sBias; C += z*sC;
  __shared__ unsigned short As_hi[64][68], As_lo[64][68];
  __shared__ unsigned short Bs_hi[128][68], Bs_lo[128][68];
  const int tid = threadIdx.x;
  const int lane = tid & 63, wv = tid >> 6;
  const int wr = wv >> 1, wc = wv & 1;
  const int mw = wr*32, nw = wc*64;
  const int la = lane & 15, kg = (lane >> 4) << 3;
  const int m0 = blockIdx.x * 64, n0 = blockIdx.y * 128;

  f32x4_t acc[2][4];
  #pragma unroll
  for (int i=0;i<2;++i)
    #pragma unroll
    for (int j=0;j<4;++j) acc[i][j] = (f32x4_t){0.f,0.f,0.f,0.f};

  for (int k0 = 0; k0 < K; k0 += 64) {
    float4 av[4]; uint4 bh4[4], bl4[4];
    #pragma unroll
    for (int r=0;r<4;++r){
      int ia = tid + r*256;
      av[r] = *(const float4*)(A + (long)(m0 + (ia>>4))*K + k0 + ((ia&15)<<2));
      int ib = tid + r*256;
      long bo = (long)(n0 + (ib>>3))*K + k0 + ((ib&7)<<3);
      bh4[r] = *(const uint4*)(Bhi + bo);
      bl4[r] = *(const uint4*)(Blo + bo);
    }
    __syncthreads();
    #pragma unroll
    for (int r=0;r<4;++r){
      int ia = tid + r*256;
      int arow = ia>>4, akc = (ia&15)<<2;
      float4 v = av[r];
      unsigned short h0=f2bf(v.x),h1=f2bf(v.y),h2=f2bf(v.z),h3=f2bf(v.w);
      uint2 whi; whi.x = (unsigned)h0 | ((unsigned)h1<<16); whi.y = (unsigned)h2 | ((unsigned)h3<<16);
      *(uint2*)&As_hi[arow][akc] = whi;
      unsigned short l0=f2bf(v.x-bf2f(h0)),l1=f2bf(v.y-bf2f(h1)),
                     l2=f2bf(v.z-bf2f(h2)),l3=f2bf(v.w-bf2f(h3));
      uint2 wlo; wlo.x = (unsigned)l0 | ((unsigned)l1<<16); wlo.y = (unsigned)l2 | ((unsigned)l3<<16);
      *(uint2*)&As_lo[arow][akc] = wlo;
      int ib = tid + r*256;
      int bn = ib>>3, bkc = (ib&7)<<3;
      uint2 t0; t0.x = bh4[r].x; t0.y = bh4[r].y;
      uint2 t1; t1.x = bh4[r].z; t1.y = bh4[r].w;
      *(uint2*)&Bs_hi[bn][bkc]   = t0;
      *(uint2*)&Bs_hi[bn][bkc+4] = t1;
      uint2 t2; t2.x = bl4[r].x; t2.y = bl4[r].y;
      uint2 t3; t3.x = bl4[r].z; t3.y = bl4[r].w;
      *(uint2*)&Bs_lo[bn][bkc]   = t2;
      *(uint2*)&Bs_lo[bn][bkc+4] = t3;
    }
    __syncthreads();
    #pragma unroll
    for (int kk=0; kk<2; ++kk){
      bf16x8_t ah[2], al[2], bh[4], bl[4];
      #pragma unroll
      for (int mf=0; mf<2; ++mf){
        ah[mf] = ldfrag(&As_hi[mw + mf*16 + la][kk*32 + kg]);
        al[mf] = ldfrag(&As_lo[mw + mf*16 + la][kk*32 + kg]);
      }
      #pragma unroll
      for (int nf=0; nf<4; ++nf){
        bh[nf] = ldfrag(&Bs_hi[nw + nf*16 + la][kk*32 + kg]);
        bl[nf] = ldfrag(&Bs_lo[nw + nf*16 + la][kk*32 + kg]);
      }
      #pragma unroll
      for (int mf=0; mf<2; ++mf)
        #pragma unroll
        for (int nf=0; nf<4; ++nf){
          acc[mf][nf] = __builtin_amdgcn_mfma_f32_16x16x32_bf16(ah[mf], bh[nf], acc[mf][nf], 0,0,0);
          acc[mf][nf] = __builtin_amdgcn_mfma_f32_16x16x32_bf16(ah[mf], bl[nf], acc[mf][nf], 0,0,0);
          acc[mf][nf] = __builtin_amdgcn_mfma_f32_16x16x32_bf16(al[mf], bh[nf], acc[mf][nf], 0,0,0);
        }
    }
  }
  #pragma unroll
  for (int mf=0; mf<2; ++mf){
    int grow0 = m0 + mw + mf*16 + ((lane>>4)<<2);
    #pragma unroll
    for (int nf=0; nf<4; ++nf){
      int gcol = n0 + nw + nf*16 + la;
      float bsv = bias[gcol];
      #pragma unroll
      for (int r=0;r<4;++r){
        int grow = grow0 + r;
        float v = acc[mf][nf][r] + bsv;
        if (EPI==1) v = geluf_(v);
        if (EPI==2) v += resid[(long)grow*N + gcol];
        C[(long)grow*N + gcol] = v;
      }
    }
  }
}

// ---------- split-bf16 MFMA GEMM, pre-split A (hi/lo bf16) ----------
// EPI: 1 = gelu -> split bf16 hi/lo out ; 3 = plain bf16 out ; 2 = fp32 +bias+resid out
template<int EPI>
__global__ __launch_bounds__(256) void gemm_mfma_s(
    const unsigned short* __restrict__ Ahi, const unsigned short* __restrict__ Alo,
    const unsigned short* __restrict__ Bhi, const unsigned short* __restrict__ Blo,
    const float* __restrict__ bias, const float* __restrict__ resid,
    float* __restrict__ Cf, unsigned short* __restrict__ Chi, unsigned short* __restrict__ Clo,
    int M, int N, int K, long sA, long sB, long sBias, long sC)
{
  int z = blockIdx.z;
  Ahi += (long)z*sA; Alo += (long)z*sA; Bhi += (long)z*sB; Blo += (long)z*sB;
  bias += (long)z*sBias;
  const long co = (long)z*sC;
  __shared__ unsigned short As_hi[64][72], As_lo[64][72];
  __shared__ unsigned short Bs_hi[128][72], Bs_lo[128][72];
  const int tid = threadIdx.x;
  const int lane = tid & 63, wv = tid >> 6;
  const int wr = wv >> 1, wc = wv & 1;
  const int mw = wr*32, nw = wc*64;
  const int la = lane & 15, kg = (lane >> 4) << 3;
  const int m0 = blockIdx.x * 64, n0 = blockIdx.y * 128;

  f32x4_t acc[2][4];
  #pragma unroll
  for (int i=0;i<2;++i)
    #pragma unroll
    for (int j=0;j<4;++j) acc[i][j] = (f32x4_t){0.f,0.f,0.f,0.f};

  for (int k0 = 0; k0 < K; k0 += 64) {
    uint4 ah4[2], al4[2], bh4[4], bl4[4];
    #pragma unroll
    for (int r=0;r<2;++r){
      int id = tid + r*256;
      long off = (long)(m0 + (id>>3))*K + k0 + ((id&7)<<3);
      ah4[r] = *(const uint4*)(Ahi + off);
      al4[r] = *(const uint4*)(Alo + off);
    }
    #pragma unroll
    for (int r=0;r<4;++r){
      int id = tid + r*256;
      long off = (long)(n0 + (id>>3))*K + k0 + ((id&7)<<3);
      bh4[r] = *(const uint4*)(Bhi + off);
      bl4[r] = *(const uint4*)(Blo + off);
    }
    __syncthreads();
    #pragma unroll
    for (int r=0;r<2;++r){
      int id = tid + r*256;
      int row = id>>3, c = (id&7)<<3;
      *(uint4*)&As_hi[row][c] = ah4[r];
      *(uint4*)&As_lo[row][c] = al4[r];
    }
    #pragma unroll
    for (int r=0;r<4;++r){
      int id = tid + r*256;
      int row = id>>3, c = (id&7)<<3;
      *(uint4*)&Bs_hi[row][c] = bh4[r];
      *(uint4*)&Bs_lo[row][c] = bl4[r];
    }
    __syncthreads();
    #pragma unroll
    for (int kk=0; kk<2; ++kk){
      bf16x8_t ah[2], al[2], bh[4], bl[4];
      #pragma unroll
      for (int mf=0; mf<2; ++mf){
        ah[mf] = ldfrag16(&As_hi[mw + mf*16 + la][kk*32 + kg]);
        al[mf] = ldfrag16(&As_lo[mw + mf*16 + la][kk*32 + kg]);
      }
      #pragma unroll
      for (int nf=0; nf<4; ++nf){
        bh[nf] = ldfrag16(&Bs_hi[nw + nf*16 + la][kk*32 + kg]);
        bl[nf] = ldfrag16(&Bs_lo[nw + nf*16 + la][kk*32 + kg]);
      }
      #pragma unroll
      for (int mf=0; mf<2; ++mf)
        #pragma unroll
        for (int nf=0; nf<4; ++nf){
          acc[mf][nf] = __builtin_amdgcn_mfma_f32_16x16x32_bf16(ah[mf], bh[nf], acc[mf][nf], 0,0,0);
          acc[mf][nf] = __builtin_amdgcn_mfma_f32_16x16x32_bf16(ah[mf], bl[nf], acc[mf][nf], 0,0,0);
          acc[mf][nf] = __builtin_amdgcn_mfma_f32_16x16x32_bf16(al[mf], bh[nf], acc[mf][nf], 0,0,0);
        }
    }
  }
  #pragma unroll
  for (int mf=0; mf<2; ++mf){
    int grow0 = m0 + mw + mf*16 + ((lane>>4)<<2);
    #pragma unroll
    for (int nf=0; nf<4; ++nf){
      int gcol = n0 + nw + nf*16 + la;
      float bsv = bias[gcol];
      #pragma unroll
      for (int r=0;r<4;++r){
        int grow = grow0 + r;
        float v = acc[mf][nf][r] + bsv;
        long idx = co + (long)grow*N + gcol;
        if (EPI==1){
          float g = geluf_(v);
          unsigned short h = f2bf(g);
          Chi[idx] = h;
          Clo[idx] = f2bf(g - bf2f(h));
        } else if (EPI==3){
          Chi[idx] = f2bf(v);
        } else { // EPI==2
          Cf[(long)grow*N + gcol] = v + resid[(long)grow*N + gcol];
        }
      }
    }
  }
}

// ---------- real = tanh(a)*cos(2pi*sigmoid(ph)); xn = LN_P(real)*g1+bt1 (hi/lo bf16) ----------
__global__ __launch_bounds__(256) void encode_ln_kernel(
    const float* __restrict__ E, const float* __restrict__ g1, const float* __restrict__ bt1,
    float* __restrict__ realp, unsigned short* __restrict__ xnh, unsigned short* __restrict__ xnl)
{
  int wv = threadIdx.x >> 6, lane = threadIdx.x & 63;
  long row = (long)blockIdx.x*4 + wv;         // 0..4095
  const float* e = E + row*256;
  int p = lane*2;
  float2 a = *(const float2*)(e + p);
  float2 f = *(const float2*)(e + 128 + p);
  const float TWO_PI = 6.28318530717958647692f;
  float r0 = tanhf(a.x) * cosf(TWO_PI * sigmoidf_(f.x));
  float r1 = tanhf(a.y) * cosf(TWO_PI * sigmoidf_(f.y));
  float s = r0+r1, ss = r0*r0 + r1*r1;
  #pragma unroll
  for (int m=1;m<64;m<<=1){ s += __shfl_xor(s,m,64); ss += __shfl_xor(ss,m,64); }
  float mean = s * (1.f/128.f);
  float var  = ss * (1.f/128.f) - mean*mean;
  float inv  = rsqrtf(var + 1e-5f);
  float x0 = (r0-mean)*inv*g1[p]   + bt1[p];
  float x1 = (r1-mean)*inv*g1[p+1] + bt1[p+1];
  *(float2*)(realp + row*128 + p) = make_float2(r0,r1);
  unsigned short h0 = f2bf(x0), h1 = f2bf(x1);
  *(unsigned int*)(xnh + row*128 + p) = (unsigned)h0 | ((unsigned)h1<<16);
  unsigned short l0 = f2bf(x0 - bf2f(h0)), l1 = f2bf(x1 - bf2f(h1));
  *(unsigned int*)(xnl + row*128 + p) = (unsigned)l0 | ((unsigned)l1<<16);
}

// ---------- per-channel autocorr via symmetry: R(lam)=R(-lam) ----------
// compute lam in [0,256], write sigmoid(R) at s=256+lam and s=256-lam. bf16 in/out.
__global__ __launch_bounds__(256) void autocorr_kernel(
    const unsigned short* __restrict__ tb, unsigned short* __restrict__ sig)
{
  __shared__ float vp[4][968];                // phys(771)=963, data 0..511, zeros above
  int bidx = blockIdx.x;                      // 0..2047
  int p4 = bidx & 31; int hb = bidx >> 5; int b = hb & 7, h = hb >> 3;
  float* vflat = &vp[0][0];
  for (int i = threadIdx.x; i < 4*968; i += 256) vflat[i] = 0.f;
  __syncthreads();
  const unsigned short* tp = tb + ((long)(h*4096 + b*512))*128 + p4*4;
  for (int idx = threadIdx.x; idx < 2048; idx += 256) {
    int s = idx >> 2, c = idx & 3;
    vp[c][s + ((s>>3)<<1)] = bf2f(tp[(long)s*128 + c]);
  }
  __syncthreads();
  int wv = threadIdx.x >> 6, lane = threadIdx.x & 63;
  const float* V = vp[wv];
  int lb = lane*4;                            // lag base: lane owns lags lb..lb+3
  float acc[4] = {0,0,0,0};
  float cur[8], nxt[8], aa[8];
  #pragma unroll
  for (int u=0;u<8;u+=2){ int li = lb+u; *(float2*)&cur[u] = *(const float2*)&V[li + ((li>>3)<<1)]; }
  for (int t0=0; t0<512; t0+=8){
    #pragma unroll
    for (int u=0;u<8;u+=2){ int li = t0+8+lb+u; *(float2*)&nxt[u] = *(const float2*)&V[li + ((li>>3)<<1)]; }
    #pragma unroll
    for (int u=0;u<8;u+=2){ int li = t0+u; *(float2*)&aa[u] = *(const float2*)&V[li + ((li>>3)<<1)]; }
    #pragma unroll
    for (int u=0;u<8;++u){
      float a = aa[u];
      #pragma unroll
      for (int j=0;j<4;++j){
        int w = u+j;
        float wl = (w<8)? cur[w] : nxt[w-8];
        acc[j] = fmaf(a, wl, acc[j]);
      }
    }
    #pragma unroll
    for (int u=0;u<8;++u) cur[u]=nxt[u];
  }
  // lag 256 edge: R(256) = sum_{t<256} v[t]v[t+256]
  float r256 = 0.f;
  #pragma unroll
  for (int u=0;u<4;++u){
    int t = lb + u; int t2 = t + 256;
    r256 = fmaf(V[t + ((t>>3)<<1)], V[t2 + ((t2>>3)<<1)], r256);
  }
  #pragma unroll
  for (int m=1;m<64;m<<=1) r256 += __shfl_xor(r256, m, 64);
  unsigned short* sp = sig + ((long)(h*4096 + b*512))*128 + p4*4 + wv;
  #pragma unroll
  for (int j=0;j<4;++j){
    int lam = lb + j;                         // 0..255
    unsigned short bv = f2bf(sigmoidf_(acc[j]));
    sp[(long)(256+lam)*128] = bv;
    if (lam > 0) sp[(long)(256-lam)*128] = bv;
  }
  if (lane == 0) sp[0] = f2bf(sigmoidf_(r256));
}

// ---------- gated = real*sig(bf16) ; y = LN_P(gated)*g2+bt2 -> hi/lo bf16 ----------
__global__ __launch_bounds__(256) void gate_ln_kernel(
    const float* __restrict__ realp, const unsigned short* __restrict__ sig,
    const float* __restrict__ g2, const float* __restrict__ bt2,
    unsigned short* __restrict__ yh, unsigned short* __restrict__ yl)
{
  int wv = threadIdx.x >> 6, lane = threadIdx.x & 63;
  long r = (long)blockIdx.x*4 + wv;           // (h,b,s) row, 0..32767
  int h = (int)(r >> 12);
  long rem = r & 4095;                        // b*512+s
  int p = lane*2;
  float2 rv = *(const float2*)(realp + rem*128 + p);
  unsigned int sv2 = *(const unsigned int*)(sig + r*128 + p);
  float s0 = bf2f((unsigned short)(sv2 & 0xffffu));
  float s1 = bf2f((unsigned short)(sv2 >> 16));
  float a0 = rv.x*s0, a1 = rv.y*s1;
  float s = a0+a1, ss = a0*a0+a1*a1;
  #pragma unroll
  for (int m=1;m<64;m<<=1){ s += __shfl_xor(s,m,64); ss += __shfl_xor(ss,m,64); }
  float mean = s*(1.f/128.f);
  float var  = ss*(1.f/128.f) - mean*mean;
  float inv  = rsqrtf(var+1e-5f);
  float y0 = (a0-mean)*inv*g2[p]   + bt2[p];
  float y1 = (a1-mean)*inv*g2[p+1] + bt2[p+1];
  long o = rem*1024 + h*128 + p;
  unsigned short h0 = f2bf(y0), h1 = f2bf(y1);
  *(unsigned int*)(yh + o) = (unsigned)h0 | ((unsigned)h1<<16);
  unsigned short l0 = f2bf(y0 - bf2f(h0)), l1 = f2bf(y1 - bf2f(h1));
  *(unsigned int*)(yl + o) = (unsigned)l0 | ((unsigned)l1<<16);
}

extern "C" void kernel_launch(void* const* d_in, const int* in_sizes, int n_in,
                              void* d_out, int out_size, void* d_ws, size_t ws_size,
                              hipStream_t stream)
{
  const float* x   = (const float*)d_in[0];
  const float* Wa  = (const float*)d_in[1];
  const float* ba  = (const float*)d_in[2];
  const float* Wp  = (const float*)d_in[3];
  const float* bp  = (const float*)d_in[4];
  const float* g1  = (const float*)d_in[5];
  const float* bt1 = (const float*)d_in[6];
  const float* W1  = (const float*)d_in[7];
  const float* bh1 = (const float*)d_in[8];
  const float* W2  = (const float*)d_in[9];
  const float* bh2 = (const float*)d_in[10];
  const float* g2  = (const float*)d_in[11];
  const float* bt2 = (const float*)d_in[12];
  const float* Wo  = (const float*)d_in[13];
  const float* bo  = (const float*)d_in[14];

  char* p = (char*)d_ws;
  auto alloc = [&](size_t bytes)->char*{ char* r = p; p += (bytes + 255) & ~(size_t)255; return r; };
  float* bcat = (float*)alloc(256*4);
  unsigned short* WcatT_hi = (unsigned short*)alloc(256*1024*2);
  unsigned short* WcatT_lo = (unsigned short*)alloc(256*1024*2);
  unsigned short* W1T_hi   = (unsigned short*)alloc(8*256*128*2);
  unsigned short* W1T_lo   = (unsigned short*)alloc(8*256*128*2);
  unsigned short* W2T_hi   = (unsigned short*)alloc(8*128*256*2);
  unsigned short* W2T_lo   = (unsigned short*)alloc(8*128*256*2);
  unsigned short* WoT_hi   = (unsigned short*)alloc(1024*1024*2);
  unsigned short* WoT_lo   = (unsigned short*)alloc(1024*1024*2);
  float* E     = (float*)alloc((size_t)4096*256*4);
  float* realp = (float*)alloc((size_t)4096*128*4);
  unsigned short* xnh = (unsigned short*)alloc((size_t)4096*128*2);
  unsigned short* xnl = (unsigned short*)alloc((size_t)4096*128*2);
  unsigned short* hidh = (unsigned short*)alloc((size_t)8*4096*256*2);
  unsigned short* hidl = (unsigned short*)alloc((size_t)8*4096*256*2);
  unsigned short* tbuf = (unsigned short*)alloc((size_t)8*4096*128*2);
  unsigned short* sigb = hidh;   // hid dead after W2-gemm (16MB >= 8MB)
  unsigned short* yh   = tbuf;   // tbuf dead after autocorr (8MB)
  unsigned short* yl   = hidl;   // hid dead (16MB >= 8MB)
  float* out   = (float*)d_out;

  bias_pack<<<1,256,0,stream>>>(ba,bp,bcat);
  transpose_split<<<dim3(4,32,1),256,0,stream>>>(Wa, WcatT_hi, WcatT_lo, 1024,128);
  transpose_split<<<dim3(4,32,1),256,0,stream>>>(Wp, WcatT_hi+131072, WcatT_lo+131072, 1024,128);
  transpose_split<<<dim3(8,4,8),256,0,stream>>>(W1, W1T_hi, W1T_lo, 128,256);
  transpose_split<<<dim3(4,8,8),256,0,stream>>>(W2, W2T_hi, W2T_lo, 256,128);
  transpose_split<<<dim3(32,32,1),256,0,stream>>>(Wo, WoT_hi, WoT_lo, 1024,1024);

  // E = x @ [Wa|Wp] + [ba|bp]   (fp32 A, on-the-fly split)
  gemm_mfma<0><<<dim3(64,2,1),256,0,stream>>>(x, WcatT_hi, WcatT_lo, bcat, nullptr, E,
                                              4096,256,1024, 0,0,0,0);
  encode_ln_kernel<<<1024,256,0,stream>>>(E,g1,bt1,realp,xnh,xnl);
  // hid[h] = gelu(xn @ W1[h] + bh1[h]) -> hi/lo bf16
  gemm_mfma_s<1><<<dim3(64,2,8),256,0,stream>>>(xnh, xnl, W1T_hi, W1T_lo, bh1, nullptr,
                                                nullptr, hidh, hidl,
                                                4096,256,128, 0, (long)256*128, 256, (long)4096*256);
  // t[h] = hid[h] @ W2[h] + bh2[h] -> bf16
  gemm_mfma_s<3><<<dim3(64,1,8),256,0,stream>>>(hidh, hidl, W2T_hi, W2T_lo, bh2, nullptr,
                                                nullptr, tbuf, nullptr,
                                                4096,128,256, (long)4096*256, (long)128*256, 128, (long)4096*128);
  autocorr_kernel<<<2048,256,0,stream>>>(tbuf, sigb);
  gate_ln_kernel<<<8192,256,0,stream>>>(realp, sigb, g2, bt2, yh, yl);
  // out = y @ Wo + bo + x
  gemm_mfma_s<2><<<dim3(64,8,1),256,0,stream>>>(yh, yl, WoT_hi, WoT_lo, bo, x,
                                                out, nullptr, nullptr,
                                                4096,1024,1024, 0,0,0,0);
}

// Round 7
// 263.221 us; speedup vs baseline: 1.3593x; 1.3593x over previous
//
#include <hip/hip_runtime.h>
#include <math.h>

// B=8, S=512, D=1024, P=128, H=8 ; rows = B*S = 4096
typedef __attribute__((ext_vector_type(8))) short bf16x8_t;
typedef __attribute__((ext_vector_type(4))) float f32x4_t;

__device__ __forceinline__ float sigmoidf_(float x){ return 1.f/(1.f+expf(-x)); }
__device__ __forceinline__ float geluf_(float x){ return 0.5f*x*(1.f+erff(x*0.70710678118654752f)); }
__device__ __forceinline__ unsigned short f2bf(float x){
  unsigned int u = __float_as_uint(x);
  return (unsigned short)((u + 0x7fffu + ((u>>16)&1u)) >> 16);
}
__device__ __forceinline__ float bf2f(unsigned short h){
  return __uint_as_float(((unsigned int)h)<<16);
}
__device__ __forceinline__ bf16x8_t ldfrag(const unsigned short* p){
  union { bf16x8_t v; uint2 q[2]; } u;
  u.q[0] = *(const uint2*)p; u.q[1] = *(const uint2*)(p+4); return u.v;
}

// ---------- bias concat ----------
__global__ __launch_bounds__(256) void bias_pack(const float* __restrict__ ba,
    const float* __restrict__ bp, float* __restrict__ bcat){
  int t = threadIdx.x; bcat[t] = (t<128)? ba[t] : bp[t-128];
}

// ---------- transpose + split fp32 -> (hi,lo) bf16 ; dst[c][r] = src[r][c] ----------
__global__ __launch_bounds__(256) void transpose_split(
    const float* __restrict__ src, unsigned short* __restrict__ dhi,
    unsigned short* __restrict__ dlo, int R, int C)
{
  long zoff = (long)blockIdx.z * R * C;
  src += zoff; dhi += zoff; dlo += zoff;
  __shared__ float tile[32][33];
  int c0 = blockIdx.x*32, r0 = blockIdx.y*32;
  int j = threadIdx.x & 31, i0 = threadIdx.x >> 5;
  #pragma unroll
  for (int ii=0; ii<4; ++ii){ int i = i0 + ii*8;
    tile[i][j] = src[(long)(r0+i)*C + c0 + j]; }
  __syncthreads();
  #pragma unroll
  for (int ii=0; ii<4; ++ii){ int i = i0 + ii*8;
    float v = tile[j][i];
    unsigned short h = f2bf(v);
    dhi[(long)(c0+i)*R + r0 + j] = h;
    dlo[(long)(c0+i)*R + r0 + j] = f2bf(v - bf2f(h));
  }
}

// ---------- split-bf16 MFMA GEMM: C = epi(A@B + bias [+resid]) ----------
// A fp32 [M][K] (split on the fly); B pre-split transposed [N][K] hi/lo bf16.
// block tile 64x128, BK=64, 4 waves (2x2), wave tile 32x64 via 16x16x32 MFMA.
// EPI: 0 = +bias ; 1 = gelu(+bias) ; 2 = +bias+resid ; 4 = +bias, store transposed C^T[N][M] (float4)
template<int EPI>
__global__ __launch_bounds__(256) void gemm_mfma(
    const float* __restrict__ A, const unsigned short* __restrict__ Bhi,
    const unsigned short* __restrict__ Blo,
    const float* __restrict__ bias, const float* __restrict__ resid,
    float* __restrict__ C, int M, int N, int K,
    long sA, long sB, long sBias, long sC)
{
  int z = blockIdx.z;
  A += (long)z*sA; Bhi += (long)z*sB; Blo += (long)z*sB; bias += (long)z*sBias; C += (long)z*sC;
  __shared__ unsigned short As_hi[64][68], As_lo[64][68];
  __shared__ unsigned short Bs_hi[128][68], Bs_lo[128][68];
  const int tid = threadIdx.x;
  const int lane = tid & 63, wv = tid >> 6;
  const int wr = wv >> 1, wc = wv & 1;
  const int mw = wr*32, nw = wc*64;
  const int la = lane & 15, kg = (lane >> 4) << 3;
  const int m0 = blockIdx.x * 64, n0 = blockIdx.y * 128;

  f32x4_t acc[2][4];
  #pragma unroll
  for (int i=0;i<2;++i)
    #pragma unroll
    for (int j=0;j<4;++j) acc[i][j] = (f32x4_t){0.f,0.f,0.f,0.f};

  for (int k0 = 0; k0 < K; k0 += 64) {
    float4 av[4]; uint4 bh4[4], bl4[4];
    #pragma unroll
    for (int r=0;r<4;++r){
      int ia = tid + r*256;
      av[r] = *(const float4*)(A + (long)(m0 + (ia>>4))*K + k0 + ((ia&15)<<2));
      int ib = tid + r*256;
      long bo = (long)(n0 + (ib>>3))*K + k0 + ((ib&7)<<3);
      bh4[r] = *(const uint4*)(Bhi + bo);
      bl4[r] = *(const uint4*)(Blo + bo);
    }
    __syncthreads();
    #pragma unroll
    for (int r=0;r<4;++r){
      int ia = tid + r*256;
      int arow = ia>>4, akc = (ia&15)<<2;
      float4 v = av[r];
      unsigned short h0=f2bf(v.x),h1=f2bf(v.y),h2=f2bf(v.z),h3=f2bf(v.w);
      uint2 whi; whi.x = (unsigned)h0 | ((unsigned)h1<<16); whi.y = (unsigned)h2 | ((unsigned)h3<<16);
      *(uint2*)&As_hi[arow][akc] = whi;
      unsigned short l0=f2bf(v.x-bf2f(h0)),l1=f2bf(v.y-bf2f(h1)),
                     l2=f2bf(v.z-bf2f(h2)),l3=f2bf(v.w-bf2f(h3));
      uint2 wlo; wlo.x = (unsigned)l0 | ((unsigned)l1<<16); wlo.y = (unsigned)l2 | ((unsigned)l3<<16);
      *(uint2*)&As_lo[arow][akc] = wlo;
      int ib = tid + r*256;
      int bn = ib>>3, bkc = (ib&7)<<3;
      uint2 t0; t0.x = bh4[r].x; t0.y = bh4[r].y;
      uint2 t1; t1.x = bh4[r].z; t1.y = bh4[r].w;
      *(uint2*)&Bs_hi[bn][bkc]   = t0;
      *(uint2*)&Bs_hi[bn][bkc+4] = t1;
      uint2 t2; t2.x = bl4[r].x; t2.y = bl4[r].y;
      uint2 t3; t3.x = bl4[r].z; t3.y = bl4[r].w;
      *(uint2*)&Bs_lo[bn][bkc]   = t2;
      *(uint2*)&Bs_lo[bn][bkc+4] = t3;
    }
    __syncthreads();
    #pragma unroll
    for (int kk=0; kk<2; ++kk){
      bf16x8_t ah[2], al[2], bh[4], bl[4];
      #pragma unroll
      for (int mf=0; mf<2; ++mf){
        ah[mf] = ldfrag(&As_hi[mw + mf*16 + la][kk*32 + kg]);
        al[mf] = ldfrag(&As_lo[mw + mf*16 + la][kk*32 + kg]);
      }
      #pragma unroll
      for (int nf=0; nf<4; ++nf){
        bh[nf] = ldfrag(&Bs_hi[nw + nf*16 + la][kk*32 + kg]);
        bl[nf] = ldfrag(&Bs_lo[nw + nf*16 + la][kk*32 + kg]);
      }
      #pragma unroll
      for (int mf=0; mf<2; ++mf)
        #pragma unroll
        for (int nf=0; nf<4; ++nf){
          acc[mf][nf] = __builtin_amdgcn_mfma_f32_16x16x32_bf16(ah[mf], bh[nf], acc[mf][nf], 0,0,0);
          acc[mf][nf] = __builtin_amdgcn_mfma_f32_16x16x32_bf16(ah[mf], bl[nf], acc[mf][nf], 0,0,0);
          acc[mf][nf] = __builtin_amdgcn_mfma_f32_16x16x32_bf16(al[mf], bh[nf], acc[mf][nf], 0,0,0);
        }
    }
  }
  // epilogue: C/D layout col=lane&15, row=(lane>>4)*4+reg
  #pragma unroll
  for (int mf=0; mf<2; ++mf){
    int grow0 = m0 + mw + mf*16 + ((lane>>4)<<2);
    #pragma unroll
    for (int nf=0; nf<4; ++nf){
      int gcol = n0 + nw + nf*16 + la;
      float bsv = bias[gcol];
      if (EPI==4){
        float4 o;
        o.x = acc[mf][nf][0] + bsv; o.y = acc[mf][nf][1] + bsv;
        o.z = acc[mf][nf][2] + bsv; o.w = acc[mf][nf][3] + bsv;
        *(float4*)(C + (long)gcol*M + grow0) = o;   // C^T[N][M], contiguous in rows
      } else {
        #pragma unroll
        for (int r=0;r<4;++r){
          int grow = grow0 + r;
          float v = acc[mf][nf][r] + bsv;
          if (EPI==1) v = geluf_(v);
          if (EPI==2) v += resid[(long)grow*N + gcol];
          C[(long)grow*N + gcol] = v;
        }
      }
    }
  }
}

// ---------- real = tanh(a)*cos(2pi*sigmoid(ph)); xn = LN_P(real)*g1+bt1 ----------
__global__ __launch_bounds__(256) void encode_ln_kernel(
    const float* __restrict__ E, const float* __restrict__ g1, const float* __restrict__ bt1,
    float* __restrict__ realp, float* __restrict__ xnp)
{
  int wv = threadIdx.x >> 6, lane = threadIdx.x & 63;
  long row = (long)blockIdx.x*4 + wv;         // 0..4095
  const float* e = E + row*256;
  int p = lane*2;
  float2 a = *(const float2*)(e + p);
  float2 f = *(const float2*)(e + 128 + p);
  const float TWO_PI = 6.28318530717958647692f;
  float r0 = tanhf(a.x) * cosf(TWO_PI * sigmoidf_(f.x));
  float r1 = tanhf(a.y) * cosf(TWO_PI * sigmoidf_(f.y));
  float s = r0+r1, ss = r0*r0 + r1*r1;
  #pragma unroll
  for (int m=1;m<64;m<<=1){ s += __shfl_xor(s,m,64); ss += __shfl_xor(ss,m,64); }
  float mean = s * (1.f/128.f);
  float var  = ss * (1.f/128.f) - mean*mean;
  float inv  = rsqrtf(var + 1e-5f);
  float x0 = (r0-mean)*inv*g1[p]   + bt1[p];
  float x1 = (r1-mean)*inv*g1[p+1] + bt1[p+1];
  *(float2*)(realp + row*128 + p) = make_float2(r0,r1);
  *(float2*)(xnp   + row*128 + p) = make_float2(x0,x1);
}

// ---------- per-channel autocorr via symmetry: R(lam)=R(-lam) ----------
// input tT[h][p][4096] (transposed, contiguous per channel), output sig[h,b,s,p] fp32.
// compute lam in [0,255] (4/lane) + lam=256 edge; write sigmoid(R) at s=256+-lam.
__global__ __launch_bounds__(256) void autocorr_kernel(
    const float* __restrict__ tT, float* __restrict__ sig)
{
  __shared__ float vp[4][968];                // phys(771)=963 max read; zeros above 512
  int bidx = blockIdx.x;                      // 0..2047
  int p4 = bidx & 31; int hb = bidx >> 5; int b = hb & 7, h = hb >> 3;
  float* vflat = &vp[0][0];
  for (int i = threadIdx.x; i < 4*968; i += 256) vflat[i] = 0.f;
  __syncthreads();
  const float* tp = tT + ((long)(h*128 + p4*4))*4096 + b*512;
  for (int idx = threadIdx.x; idx < 2048; idx += 256) {
    int c = idx >> 9, s = idx & 511;          // contiguous, coalesced
    vp[c][s + ((s>>3)<<1)] = tp[(long)c*4096 + s];
  }
  __syncthreads();
  int wv = threadIdx.x >> 6, lane = threadIdx.x & 63;
  const float* V = vp[wv];
  int lb = lane*4;                            // lag base: lane owns lags lb..lb+3
  float acc[4] = {0,0,0,0};
  float cur[8], nxt[8], aa[8];
  #pragma unroll
  for (int u=0;u<8;u+=2){ int li = lb+u; *(float2*)&cur[u] = *(const float2*)&V[li + ((li>>3)<<1)]; }
  for (int t0=0; t0<512; t0+=8){
    #pragma unroll
    for (int u=0;u<8;u+=2){ int li = t0+8+lb+u; *(float2*)&nxt[u] = *(const float2*)&V[li + ((li>>3)<<1)]; }
    #pragma unroll
    for (int u=0;u<8;u+=2){ int li = t0+u; *(float2*)&aa[u] = *(const float2*)&V[li + ((li>>3)<<1)]; }
    #pragma unroll
    for (int u=0;u<8;++u){
      float a = aa[u];
      #pragma unroll
      for (int j=0;j<4;++j){
        int w = u+j;
        float wl = (w<8)? cur[w] : nxt[w-8];
        acc[j] = fmaf(a, wl, acc[j]);
      }
    }
    #pragma unroll
    for (int u=0;u<8;++u) cur[u]=nxt[u];
  }
  // lag 256 edge: R(256) = sum_{t<256} v[t]v[t+256]
  float r256 = 0.f;
  #pragma unroll
  for (int u=0;u<4;++u){
    int t = lb + u; int t2 = t + 256;
    r256 = fmaf(V[t + ((t>>3)<<1)], V[t2 + ((t2>>3)<<1)], r256);
  }
  #pragma unroll
  for (int m=1;m<64;m<<=1) r256 += __shfl_xor(r256, m, 64);
  float* sp = sig + ((long)(h*4096 + b*512))*128 + p4*4 + wv;
  #pragma unroll
  for (int j=0;j<4;++j){
    int lam = lb + j;                         // 0..255
    float bv = sigmoidf_(acc[j]);
    sp[(long)(256+lam)*128] = bv;
    if (lam > 0) sp[(long)(256-lam)*128] = bv;
  }
  if (lane == 0) sp[0] = sigmoidf_(r256);
}

// ---------- gated = real*sig ; y[b,s,h*128+p] = LN_P(gated)*g2+bt2 ----------
__global__ __launch_bounds__(256) void gate_ln_kernel(
    const float* __restrict__ realp, const float* __restrict__ sig,
    const float* __restrict__ g2, const float* __restrict__ bt2,
    float* __restrict__ y)
{
  int wv = threadIdx.x >> 6, lane = threadIdx.x & 63;
  long r = (long)blockIdx.x*4 + wv;           // (h,b,s) row, 0..32767
  int h = (int)(r >> 12);
  long rem = r & 4095;                        // b*512+s
  int p = lane*2;
  float2 rv = *(const float2*)(realp + rem*128 + p);
  float2 sv = *(const float2*)(sig + r*128 + p);
  float a0 = rv.x*sv.x, a1 = rv.y*sv.y;
  float s = a0+a1, ss = a0*a0+a1*a1;
  #pragma unroll
  for (int m=1;m<64;m<<=1){ s += __shfl_xor(s,m,64); ss += __shfl_xor(ss,m,64); }
  float mean = s*(1.f/128.f);
  float var  = ss*(1.f/128.f) - mean*mean;
  float inv  = rsqrtf(var+1e-5f);
  float y0 = (a0-mean)*inv*g2[p]   + bt2[p];
  float y1 = (a1-mean)*inv*g2[p+1] + bt2[p+1];
  *(float2*)(y + rem*1024 + h*128 + p) = make_float2(y0,y1);
}

extern "C" void kernel_launch(void* const* d_in, const int* in_sizes, int n_in,
                              void* d_out, int out_size, void* d_ws, size_t ws_size,
                              hipStream_t stream)
{
  const float* x   = (const float*)d_in[0];
  const float* Wa  = (const float*)d_in[1];
  const float* ba  = (const float*)d_in[2];
  const float* Wp  = (const float*)d_in[3];
  const float* bp  = (const float*)d_in[4];
  const float* g1  = (const float*)d_in[5];
  const float* bt1 = (const float*)d_in[6];
  const float* W1  = (const float*)d_in[7];
  const float* bh1 = (const float*)d_in[8];
  const float* W2  = (const float*)d_in[9];
  const float* bh2 = (const float*)d_in[10];
  const float* g2  = (const float*)d_in[11];
  const float* bt2 = (const float*)d_in[12];
  const float* Wo  = (const float*)d_in[13];
  const float* bo  = (const float*)d_in[14];

  char* p = (char*)d_ws;
  auto alloc = [&](size_t bytes)->char*{ char* r = p; p += (bytes + 255) & ~(size_t)255; return r; };
  float* bcat = (float*)alloc(256*4);
  unsigned short* WcatT_hi = (unsigned short*)alloc(256*1024*2);
  unsigned short* WcatT_lo = (unsigned short*)alloc(256*1024*2);
  unsigned short* W1T_hi   = (unsigned short*)alloc(8*256*128*2);
  unsigned short* W1T_lo   = (unsigned short*)alloc(8*256*128*2);
  unsigned short* W2T_hi   = (unsigned short*)alloc(8*128*256*2);
  unsigned short* W2T_lo   = (unsigned short*)alloc(8*128*256*2);
  unsigned short* WoT_hi   = (unsigned short*)alloc(1024*1024*2);
  unsigned short* WoT_lo   = (unsigned short*)alloc(1024*1024*2);
  float* E     = (float*)alloc((size_t)4096*256*4);
  float* realp = (float*)alloc((size_t)4096*128*4);
  float* xnp   = (float*)alloc((size_t)4096*128*4);
  float* hid   = (float*)alloc((size_t)8*4096*256*4);
  float* tbuf  = (float*)alloc((size_t)8*128*4096*4);   // t^T [h][p][4096]
  float* sigb  = hid;    // hid (32MB) dead after W2-gemm; sig fp32 16MB
  float* ybuf  = tbuf;   // tT dead after autocorr
  float* out   = (float*)d_out;

  bias_pack<<<1,256,0,stream>>>(ba,bp,bcat);
  transpose_split<<<dim3(4,32,1),256,0,stream>>>(Wa, WcatT_hi, WcatT_lo, 1024,128);
  transpose_split<<<dim3(4,32,1),256,0,stream>>>(Wp, WcatT_hi+131072, WcatT_lo+131072, 1024,128);
  transpose_split<<<dim3(8,4,8),256,0,stream>>>(W1, W1T_hi, W1T_lo, 128,256);
  transpose_split<<<dim3(4,8,8),256,0,stream>>>(W2, W2T_hi, W2T_lo, 256,128);
  transpose_split<<<dim3(32,32,1),256,0,stream>>>(Wo, WoT_hi, WoT_lo, 1024,1024);

  // E = x @ [Wa|Wp] + [ba|bp]
  gemm_mfma<0><<<dim3(64,2,1),256,0,stream>>>(x, WcatT_hi, WcatT_lo, bcat, nullptr, E,
                                              4096,256,1024, 0,0,0,0);
  encode_ln_kernel<<<1024,256,0,stream>>>(E,g1,bt1,realp,xnp);
  // hid[h] = gelu(xn @ W1[h] + bh1[h])
  gemm_mfma<1><<<dim3(64,2,8),256,0,stream>>>(xnp, W1T_hi, W1T_lo, bh1, nullptr, hid,
                                              4096,256,128, 0, (long)256*128, 256, (long)4096*256);
  // tT[h] = (hid[h] @ W2[h] + bh2[h])^T  (transposed contiguous store)
  gemm_mfma<4><<<dim3(64,1,8),256,0,stream>>>(hid, W2T_hi, W2T_lo, bh2, nullptr, tbuf,
                                              4096,128,256, (long)4096*256, (long)128*256, 128, (long)128*4096);
  autocorr_kernel<<<2048,256,0,stream>>>(tbuf, sigb);
  gate_ln_kernel<<<8192,256,0,stream>>>(realp, sigb, g2, bt2, ybuf);
  // out = y @ Wo + bo + x
  gemm_mfma<2><<<dim3(64,8,1),256,0,stream>>>(ybuf, WoT_hi, WoT_lo, bo, x, out,
                                              4096,1024,1024, 0,0,0,0);
}

// Round 9
// 257.564 us; speedup vs baseline: 1.3892x; 1.0220x over previous
//
#include <hip/hip_runtime.h>
#include <math.h>

// B=8, S=512, D=1024, P=128, H=8 ; rows = B*S = 4096
typedef __attribute__((ext_vector_type(8))) short bf16x8_t;
typedef __attribute__((ext_vector_type(4))) float f32x4_t;

__device__ __forceinline__ float sigmoidf_(float x){ return 1.f/(1.f+expf(-x)); }
__device__ __forceinline__ float geluf_(float x){ return 0.5f*x*(1.f+erff(x*0.70710678118654752f)); }
__device__ __forceinline__ unsigned short f2bf(float x){
  unsigned int u = __float_as_uint(x);
  return (unsigned short)((u + 0x7fffu + ((u>>16)&1u)) >> 16);
}
__device__ __forceinline__ float bf2f(unsigned short h){
  return __uint_as_float(((unsigned int)h)<<16);
}
__device__ __forceinline__ bf16x8_t ldfrag(const unsigned short* p){
  union { bf16x8_t v; uint2 q[2]; } u;
  u.q[0] = *(const uint2*)p; u.q[1] = *(const uint2*)(p+4); return u.v;
}
__device__ __forceinline__ bf16x8_t ldfrag16(const unsigned short* p){
  union { bf16x8_t v; uint4 q; } u; u.q = *(const uint4*)p; return u.v;
}

// ---------- bias concat ----------
__global__ __launch_bounds__(256) void bias_pack(const float* __restrict__ ba,
    const float* __restrict__ bp, float* __restrict__ bcat){
  int t = threadIdx.x; bcat[t] = (t<128)? ba[t] : bp[t-128];
}

// ---------- transpose + split fp32 -> (hi,lo) bf16 ; dst[c][r] = src[r][c] ----------
__global__ __launch_bounds__(256) void transpose_split(
    const float* __restrict__ src, unsigned short* __restrict__ dhi,
    unsigned short* __restrict__ dlo, int R, int C)
{
  long zoff = (long)blockIdx.z * R * C;
  src += zoff; dhi += zoff; dlo += zoff;
  __shared__ float tile[32][33];
  int c0 = blockIdx.x*32, r0 = blockIdx.y*32;
  int j = threadIdx.x & 31, i0 = threadIdx.x >> 5;
  #pragma unroll
  for (int ii=0; ii<4; ++ii){ int i = i0 + ii*8;
    tile[i][j] = src[(long)(r0+i)*C + c0 + j]; }
  __syncthreads();
  #pragma unroll
  for (int ii=0; ii<4; ++ii){ int i = i0 + ii*8;
    float v = tile[j][i];
    unsigned short h = f2bf(v);
    dhi[(long)(c0+i)*R + r0 + j] = h;
    dlo[(long)(c0+i)*R + r0 + j] = f2bf(v - bf2f(h));
  }
}

// ---------- split-bf16 MFMA GEMM: C = epi(A@B + bias [+resid]) ----------
// A fp32 [M][K] (split on the fly); B pre-split transposed [N][K] hi/lo bf16.
// block tile 64x128, BK=64, 4 waves (2x2), wave tile 32x64 via 16x16x32 MFMA.
// EPI: 0 = +bias ; 1 = gelu(+bias) ; 2 = +bias+resid ; 4 = +bias, store transposed C^T[N][M] (float4)
template<int EPI>
__global__ __launch_bounds__(256) void gemm_mfma(
    const float* __restrict__ A, const unsigned short* __restrict__ Bhi,
    const unsigned short* __restrict__ Blo,
    const float* __restrict__ bias, const float* __restrict__ resid,
    float* __restrict__ C, int M, int N, int K,
    long sA, long sB, long sBias, long sC)
{
  int z = blockIdx.z;
  A += (long)z*sA; Bhi += (long)z*sB; Blo += (long)z*sB; bias += (long)z*sBias; C += (long)z*sC;
  __shared__ unsigned short As_hi[64][68], As_lo[64][68];
  __shared__ unsigned short Bs_hi[128][68], Bs_lo[128][68];
  const int tid = threadIdx.x;
  const int lane = tid & 63, wv = tid >> 6;
  const int wr = wv >> 1, wc = wv & 1;
  const int mw = wr*32, nw = wc*64;
  const int la = lane & 15, kg = (lane >> 4) << 3;
  const int m0 = blockIdx.x * 64, n0 = blockIdx.y * 128;

  f32x4_t acc[2][4];
  #pragma unroll
  for (int i=0;i<2;++i)
    #pragma unroll
    for (int j=0;j<4;++j) acc[i][j] = (f32x4_t){0.f,0.f,0.f,0.f};

  for (int k0 = 0; k0 < K; k0 += 64) {
    float4 av[4]; uint4 bh4[4], bl4[4];
    #pragma unroll
    for (int r=0;r<4;++r){
      int ia = tid + r*256;
      av[r] = *(const float4*)(A + (long)(m0 + (ia>>4))*K + k0 + ((ia&15)<<2));
      int ib = tid + r*256;
      long bo = (long)(n0 + (ib>>3))*K + k0 + ((ib&7)<<3);
      bh4[r] = *(const uint4*)(Bhi + bo);
      bl4[r] = *(const uint4*)(Blo + bo);
    }
    __syncthreads();
    #pragma unroll
    for (int r=0;r<4;++r){
      int ia = tid + r*256;
      int arow = ia>>4, akc = (ia&15)<<2;
      float4 v = av[r];
      unsigned short h0=f2bf(v.x),h1=f2bf(v.y),h2=f2bf(v.z),h3=f2bf(v.w);
      uint2 whi; whi.x = (unsigned)h0 | ((unsigned)h1<<16); whi.y = (unsigned)h2 | ((unsigned)h3<<16);
      *(uint2*)&As_hi[arow][akc] = whi;
      unsigned short l0=f2bf(v.x-bf2f(h0)),l1=f2bf(v.y-bf2f(h1)),
                     l2=f2bf(v.z-bf2f(h2)),l3=f2bf(v.w-bf2f(h3));
      uint2 wlo; wlo.x = (unsigned)l0 | ((unsigned)l1<<16); wlo.y = (unsigned)l2 | ((unsigned)l3<<16);
      *(uint2*)&As_lo[arow][akc] = wlo;
      int ib = tid + r*256;
      int bn = ib>>3, bkc = (ib&7)<<3;
      uint2 t0; t0.x = bh4[r].x; t0.y = bh4[r].y;
      uint2 t1; t1.x = bh4[r].z; t1.y = bh4[r].w;
      *(uint2*)&Bs_hi[bn][bkc]   = t0;
      *(uint2*)&Bs_hi[bn][bkc+4] = t1;
      uint2 t2; t2.x = bl4[r].x; t2.y = bl4[r].y;
      uint2 t3; t3.x = bl4[r].z; t3.y = bl4[r].w;
      *(uint2*)&Bs_lo[bn][bkc]   = t2;
      *(uint2*)&Bs_lo[bn][bkc+4] = t3;
    }
    __syncthreads();
    #pragma unroll
    for (int kk=0; kk<2; ++kk){
      bf16x8_t ah[2], al[2], bh[4], bl[4];
      #pragma unroll
      for (int mf=0; mf<2; ++mf){
        ah[mf] = ldfrag(&As_hi[mw + mf*16 + la][kk*32 + kg]);
        al[mf] = ldfrag(&As_lo[mw + mf*16 + la][kk*32 + kg]);
      }
      #pragma unroll
      for (int nf=0; nf<4; ++nf){
        bh[nf] = ldfrag(&Bs_hi[nw + nf*16 + la][kk*32 + kg]);
        bl[nf] = ldfrag(&Bs_lo[nw + nf*16 + la][kk*32 + kg]);
      }
      #pragma unroll
      for (int mf=0; mf<2; ++mf)
        #pragma unroll
        for (int nf=0; nf<4; ++nf){
          acc[mf][nf] = __builtin_amdgcn_mfma_f32_16x16x32_bf16(ah[mf], bh[nf], acc[mf][nf], 0,0,0);
          acc[mf][nf] = __builtin_amdgcn_mfma_f32_16x16x32_bf16(ah[mf], bl[nf], acc[mf][nf], 0,0,0);
          acc[mf][nf] = __builtin_amdgcn_mfma_f32_16x16x32_bf16(al[mf], bh[nf], acc[mf][nf], 0,0,0);
        }
    }
  }
  // epilogue: C/D layout col=lane&15, row=(lane>>4)*4+reg
  #pragma unroll
  for (int mf=0; mf<2; ++mf){
    int grow0 = m0 + mw + mf*16 + ((lane>>4)<<2);
    #pragma unroll
    for (int nf=0; nf<4; ++nf){
      int gcol = n0 + nw + nf*16 + la;
      float bsv = bias[gcol];
      if (EPI==4){
        float4 o;
        o.x = acc[mf][nf][0] + bsv; o.y = acc[mf][nf][1] + bsv;
        o.z = acc[mf][nf][2] + bsv; o.w = acc[mf][nf][3] + bsv;
        *(float4*)(C + (long)gcol*M + grow0) = o;   // C^T[N][M], contiguous in rows
      } else {
        #pragma unroll
        for (int r=0;r<4;++r){
          int grow = grow0 + r;
          float v = acc[mf][nf][r] + bsv;
          if (EPI==1) v = geluf_(v);
          if (EPI==2) v += resid[(long)grow*N + gcol];
          C[(long)grow*N + gcol] = v;
        }
      }
    }
  }
}

// ---------- real = tanh(a)*cos(2pi*sigmoid(ph)); xn = LN_P(real)*g1+bt1 ----------
__global__ __launch_bounds__(256) void encode_ln_kernel(
    const float* __restrict__ E, const float* __restrict__ g1, const float* __restrict__ bt1,
    float* __restrict__ realp, float* __restrict__ xnp)
{
  int wv = threadIdx.x >> 6, lane = threadIdx.x & 63;
  long row = (long)blockIdx.x*4 + wv;         // 0..4095
  const float* e = E + row*256;
  int p = lane*2;
  float2 a = *(const float2*)(e + p);
  float2 f = *(const float2*)(e + 128 + p);
  const float TWO_PI = 6.28318530717958647692f;
  float r0 = tanhf(a.x) * cosf(TWO_PI * sigmoidf_(f.x));
  float r1 = tanhf(a.y) * cosf(TWO_PI * sigmoidf_(f.y));
  float s = r0+r1, ss = r0*r0 + r1*r1;
  #pragma unroll
  for (int m=1;m<64;m<<=1){ s += __shfl_xor(s,m,64); ss += __shfl_xor(ss,m,64); }
  float mean = s * (1.f/128.f);
  float var  = ss * (1.f/128.f) - mean*mean;
  float inv  = rsqrtf(var + 1e-5f);
  float x0 = (r0-mean)*inv*g1[p]   + bt1[p];
  float x1 = (r1-mean)*inv*g1[p+1] + bt1[p+1];
  *(float2*)(realp + row*128 + p) = make_float2(r0,r1);
  *(float2*)(xnp   + row*128 + p) = make_float2(x0,x1);
}

// ---------- autocorr via MFMA: R(16a+b) = sum_t v[t+16a]*v[t-b], K=544 ----------
// Hankel operands from LDS. 4 shifted copies (d=0..3) make all B b64-reads aligned;
// copy0 (also A's operand) padded +8 ushorts per 64 so A's stride-16 reads spread banks.
// split-bf16 (hi/lo, 3 MFMAs) keeps fp32-level accuracy. lam=256 edge via VALU.
// per-channel LDS map (ushort offsets): c0h[896]@0, c0l[896]@896,
//   c1h[640]@1792, c1l@2432, c2h@3072, c2l@3712, c3h@4352, c3l@4992  (5632 total)
__device__ __forceinline__ int hi_off_(int d){ return d ? (512 + d*1280) : 0; }
__device__ __forceinline__ int lo_off_(int d){ return d ? (1152 + d*1280) : 896; }
__device__ __forceinline__ int physpad_(int m){ return m + ((m >> 6) << 3); }

__global__ __launch_bounds__(256) void autocorr_kernel(
    const float* __restrict__ tT, float* __restrict__ sig)
{
  __shared__ __align__(16) unsigned short pool[4][5632];
  const int tid = threadIdx.x;
  const int wv = tid >> 6, lane = tid & 63;
  int bidx = blockIdx.x;                      // 0..2047
  int p4 = bidx & 31; int hb = bidx >> 5; int b = hb & 7, h = hb >> 3;

  // zero-init whole pool
  unsigned int* pz = (unsigned int*)&pool[0][0];
  for (int i = tid; i < 4*5632/2; i += 256) pz[i] = 0u;
  __syncthreads();

  // stage channel p = p4*4 + wv : logical v[i], copy d at phys(i+16-d)
  unsigned short* P = pool[wv];
  {
    const float* tp = tT + ((long)(h*128 + p4*4 + wv))*4096 + b*512;
    for (int i = lane; i < 512; i += 64) {
      float v = tp[i];
      unsigned short hh = f2bf(v);
      unsigned short ll = f2bf(v - bf2f(hh));
      #pragma unroll
      for (int d = 0; d < 4; ++d) {
        int ph = physpad_(i + 16 - d);
        P[hi_off_(d) + ph] = hh;
        P[lo_off_(d) + ph] = ll;
      }
    }
  }
  __syncthreads();

  const int la = lane & 15, kg8 = (lane >> 4) << 3;
  f32x4_t acc = (f32x4_t){0.f,0.f,0.f,0.f};
  for (int kb = 0; kb < 17; ++kb) {
    // A[a][k] = v[k + 16a] : a=la, k = 32kb + kg8 + u ; q mult of 8 -> copy0, b128
    int qA = kb*32 + kg8 + la*16 + 16;
    int phA = physpad_(qA);
    bf16x8_t Ah = ldfrag16(P + phA);
    bf16x8_t Al = ldfrag16(P + 896 + phA);
    // B[k][j] = v[k - j] : j=la ; q = 32kb + kg8 + 16 - la ; copy d = q&3, 2x b64
    int qB = kb*32 + kg8 + 16 - la;
    int d = qB & 3;
    int r0 = qB - d, r1 = r0 + 4;
    int ph0 = physpad_(r0), ph1 = physpad_(r1);
    int hio = hi_off_(d), loo = lo_off_(d);
    union { bf16x8_t v; uint2 q[2]; } ub, vb;
    ub.q[0] = *(const uint2*)(P + hio + ph0);
    ub.q[1] = *(const uint2*)(P + hio + ph1);
    vb.q[0] = *(const uint2*)(P + loo + ph0);
    vb.q[1] = *(const uint2*)(P + loo + ph1);
    acc = __builtin_amdgcn_mfma_f32_16x16x32_bf16(Ah, ub.v, acc, 0,0,0);
    acc = __builtin_amdgcn_mfma_f32_16x16x32_bf16(Ah, vb.v, acc, 0,0,0);
    acc = __builtin_amdgcn_mfma_f32_16x16x32_bf16(Al, ub.v, acc, 0,0,0);
  }

  // lag 256 edge: R(256) = sum_{t<256} v[t]v[t+256] ; 4 t per lane
  float r256 = 0.f;
  #pragma unroll
  for (int u = 0; u < 4; ++u) {
    int t = lane*4 + u;
    int p1 = physpad_(t + 16), p2 = physpad_(t + 272);
    float v1 = bf2f(P[p1]) + bf2f(P[896 + p1]);
    float v2 = bf2f(P[p2]) + bf2f(P[896 + p2]);
    r256 = fmaf(v1, v2, r256);
  }
  #pragma unroll
  for (int m = 1; m < 64; m <<= 1) r256 += __shfl_xor(r256, m, 64);

  // C/D layout: col=lane&15 (=b), row=(lane>>4)*4+reg (=a); lam = 16a + b
  float* sp = sig + ((long)(h*4096 + b*512))*128 + p4*4 + wv;
  int arow = (lane >> 4) << 2;
  #pragma unroll
  for (int rr = 0; rr < 4; ++rr) {
    int lam = (arow + rr)*16 + la;            // 0..255, each exactly once
    float bv = sigmoidf_(acc[rr]);
    sp[(long)(256+lam)*128] = bv;
    if (lam > 0) sp[(long)(256-lam)*128] = bv;
  }
  if (lane == 0) sp[0] = sigmoidf_(r256);
}

// ---------- gated = real*sig ; y[b,s,h*128+p] = LN_P(gated)*g2+bt2 ----------
__global__ __launch_bounds__(256) void gate_ln_kernel(
    const float* __restrict__ realp, const float* __restrict__ sig,
    const float* __restrict__ g2, const float* __restrict__ bt2,
    float* __restrict__ y)
{
  int wv = threadIdx.x >> 6, lane = threadIdx.x & 63;
  long r = (long)blockIdx.x*4 + wv;           // (h,b,s) row, 0..32767
  int h = (int)(r >> 12);
  long rem = r & 4095;                        // b*512+s
  int p = lane*2;
  float2 rv = *(const float2*)(realp + rem*128 + p);
  float2 sv = *(const float2*)(sig + r*128 + p);
  float a0 = rv.x*sv.x, a1 = rv.y*sv.y;
  float s = a0+a1, ss = a0*a0+a1*a1;
  #pragma unroll
  for (int m=1;m<64;m<<=1){ s += __shfl_xor(s,m,64); ss += __shfl_xor(ss,m,64); }
  float mean = s*(1.f/128.f);
  float var  = ss*(1.f/128.f) - mean*mean;
  float inv  = rsqrtf(var+1e-5f);
  float y0 = (a0-mean)*inv*g2[p]   + bt2[p];
  float y1 = (a1-mean)*inv*g2[p+1] + bt2[p+1];
  *(float2*)(y + rem*1024 + h*128 + p) = make_float2(y0,y1);
}

extern "C" void kernel_launch(void* const* d_in, const int* in_sizes, int n_in,
                              void* d_out, int out_size, void* d_ws, size_t ws_size,
                              hipStream_t stream)
{
  const float* x   = (const float*)d_in[0];
  const float* Wa  = (const float*)d_in[1];
  const float* ba  = (const float*)d_in[2];
  const float* Wp  = (const float*)d_in[3];
  const float* bp  = (const float*)d_in[4];
  const float* g1  = (const float*)d_in[5];
  const float* bt1 = (const float*)d_in[6];
  const float* W1  = (const float*)d_in[7];
  const float* bh1 = (const float*)d_in[8];
  const float* W2  = (const float*)d_in[9];
  const float* bh2 = (const float*)d_in[10];
  const float* g2  = (const float*)d_in[11];
  const float* bt2 = (const float*)d_in[12];
  const float* Wo  = (const float*)d_in[13];
  const float* bo  = (const float*)d_in[14];

  char* p = (char*)d_ws;
  auto alloc = [&](size_t bytes)->char*{ char* r = p; p += (bytes + 255) & ~(size_t)255; return r; };
  float* bcat = (float*)alloc(256*4);
  unsigned short* WcatT_hi = (unsigned short*)alloc(256*1024*2);
  unsigned short* WcatT_lo = (unsigned short*)alloc(256*1024*2);
  unsigned short* W1T_hi   = (unsigned short*)alloc(8*256*128*2);
  unsigned short* W1T_lo   = (unsigned short*)alloc(8*256*128*2);
  unsigned short* W2T_hi   = (unsigned short*)alloc(8*128*256*2);
  unsigned short* W2T_lo   = (unsigned short*)alloc(8*128*256*2);
  unsigned short* WoT_hi   = (unsigned short*)alloc(1024*1024*2);
  unsigned short* WoT_lo   = (unsigned short*)alloc(1024*1024*2);
  float* E     = (float*)alloc((size_t)4096*256*4);
  float* realp = (float*)alloc((size_t)4096*128*4);
  float* xnp   = (float*)alloc((size_t)4096*128*4);
  float* hid   = (float*)alloc((size_t)8*4096*256*4);
  float* tbuf  = (float*)alloc((size_t)8*128*4096*4);   // t^T [h][p][4096]
  float* sigb  = hid;    // hid (32MB) dead after W2-gemm; sig fp32 16MB
  float* ybuf  = tbuf;   // tT dead after autocorr
  float* out   = (float*)d_out;

  bias_pack<<<1,256,0,stream>>>(ba,bp,bcat);
  transpose_split<<<dim3(4,32,1),256,0,stream>>>(Wa, WcatT_hi, WcatT_lo, 1024,128);
  transpose_split<<<dim3(4,32,1),256,0,stream>>>(Wp, WcatT_hi+131072, WcatT_lo+131072, 1024,128);
  transpose_split<<<dim3(8,4,8),256,0,stream>>>(W1, W1T_hi, W1T_lo, 128,256);
  transpose_split<<<dim3(4,8,8),256,0,stream>>>(W2, W2T_hi, W2T_lo, 256,128);
  transpose_split<<<dim3(32,32,1),256,0,stream>>>(Wo, WoT_hi, WoT_lo, 1024,1024);

  // E = x @ [Wa|Wp] + [ba|bp]
  gemm_mfma<0><<<dim3(64,2,1),256,0,stream>>>(x, WcatT_hi, WcatT_lo, bcat, nullptr, E,
                                              4096,256,1024, 0,0,0,0);
  encode_ln_kernel<<<1024,256,0,stream>>>(E,g1,bt1,realp,xnp);
  // hid[h] = gelu(xn @ W1[h] + bh1[h])
  gemm_mfma<1><<<dim3(64,2,8),256,0,stream>>>(xnp, W1T_hi, W1T_lo, bh1, nullptr, hid,
                                              4096,256,128, 0, (long)256*128, 256, (long)4096*256);
  // tT[h] = (hid[h] @ W2[h] + bh2[h])^T  (transposed contiguous store)
  gemm_mfma<4><<<dim3(64,1,8),256,0,stream>>>(hid, W2T_hi, W2T_lo, bh2, nullptr, tbuf,
                                              4096,128,256, (long)4096*256, (long)128*256, 128, (long)128*4096);
  autocorr_kernel<<<2048,256,0,stream>>>(tbuf, sigb);
  gate_ln_kernel<<<8192,256,0,stream>>>(realp, sigb, g2, bt2, ybuf);
  // out = y @ Wo + bo + x
  gemm_mfma<2><<<dim3(64,8,1),256,0,stream>>>(ybuf, WoT_hi, WoT_lo, bo, x, out,
                                              4096,1024,1024, 0,0,0,0);
}

// Round 11
// 250.913 us; speedup vs baseline: 1.4260x; 1.0265x over previous
//
#include <hip/hip_runtime.h>
#include <math.h>

// B=8, S=512, D=1024, P=128, H=8 ; rows = B*S = 4096
typedef __attribute__((ext_vector_type(8))) short bf16x8_t;
typedef __attribute__((ext_vector_type(4))) float f32x4_t;

__device__ __forceinline__ float sigmoidf_(float x){ return 1.f/(1.f+expf(-x)); }
__device__ __forceinline__ float geluf_(float x){ return 0.5f*x*(1.f+erff(x*0.70710678118654752f)); }
__device__ __forceinline__ unsigned short f2bf(float x){
  unsigned int u = __float_as_uint(x);
  return (unsigned short)((u + 0x7fffu + ((u>>16)&1u)) >> 16);
}
__device__ __forceinline__ float bf2f(unsigned short h){
  return __uint_as_float(((unsigned int)h)<<16);
}
__device__ __forceinline__ bf16x8_t ldfrag(const unsigned short* p){
  union { bf16x8_t v; uint2 q[2]; } u;
  u.q[0] = *(const uint2*)p; u.q[1] = *(const uint2*)(p+4); return u.v;
}
__device__ __forceinline__ bf16x8_t ldfrag16(const unsigned short* p){
  union { bf16x8_t v; uint4 q; } u; u.q = *(const uint4*)p; return u.v;
}

// ---------- bias concat ----------
__global__ __launch_bounds__(256) void bias_pack(const float* __restrict__ ba,
    const float* __restrict__ bp, float* __restrict__ bcat){
  int t = threadIdx.x; bcat[t] = (t<128)? ba[t] : bp[t-128];
}

// ---------- transpose + split fp32 -> (hi,lo) bf16 ; dst[c][r] = src[r][c] ----------
__global__ __launch_bounds__(256) void transpose_split(
    const float* __restrict__ src, unsigned short* __restrict__ dhi,
    unsigned short* __restrict__ dlo, int R, int C)
{
  long zoff = (long)blockIdx.z * R * C;
  src += zoff; dhi += zoff; dlo += zoff;
  __shared__ float tile[32][33];
  int c0 = blockIdx.x*32, r0 = blockIdx.y*32;
  int j = threadIdx.x & 31, i0 = threadIdx.x >> 5;
  #pragma unroll
  for (int ii=0; ii<4; ++ii){ int i = i0 + ii*8;
    tile[i][j] = src[(long)(r0+i)*C + c0 + j]; }
  __syncthreads();
  #pragma unroll
  for (int ii=0; ii<4; ++ii){ int i = i0 + ii*8;
    float v = tile[j][i];
    unsigned short h = f2bf(v);
    dhi[(long)(c0+i)*R + r0 + j] = h;
    dlo[(long)(c0+i)*R + r0 + j] = f2bf(v - bf2f(h));
  }
}

// ---------- split-bf16 MFMA GEMM: C = epi(A@B + bias) ----------
// A fp32 [M][K] (split on the fly); B pre-split transposed [N][K] hi/lo bf16.
// block tile 64x128, BK=64, 4 waves (2x2), wave tile 32x64 via 16x16x32 MFMA.
// EPI: 0 = +bias ; 1 = gelu(+bias) ; 4 = +bias, store transposed C^T[N][M] (float4)
template<int EPI>
__global__ __launch_bounds__(256) void gemm_mfma(
    const float* __restrict__ A, const unsigned short* __restrict__ Bhi,
    const unsigned short* __restrict__ Blo,
    const float* __restrict__ bias, const float* __restrict__ resid,
    float* __restrict__ C, int M, int N, int K,
    long sA, long sB, long sBias, long sC)
{
  int z = blockIdx.z;
  A += (long)z*sA; Bhi += (long)z*sB; Blo += (long)z*sB; bias += (long)z*sBias; C += (long)z*sC;
  __shared__ unsigned short As_hi[64][68], As_lo[64][68];
  __shared__ unsigned short Bs_hi[128][68], Bs_lo[128][68];
  const int tid = threadIdx.x;
  const int lane = tid & 63, wv = tid >> 6;
  const int wr = wv >> 1, wc = wv & 1;
  const int mw = wr*32, nw = wc*64;
  const int la = lane & 15, kg = (lane >> 4) << 3;
  const int m0 = blockIdx.x * 64, n0 = blockIdx.y * 128;

  f32x4_t acc[2][4];
  #pragma unroll
  for (int i=0;i<2;++i)
    #pragma unroll
    for (int j=0;j<4;++j) acc[i][j] = (f32x4_t){0.f,0.f,0.f,0.f};

  for (int k0 = 0; k0 < K; k0 += 64) {
    float4 av[4]; uint4 bh4[4], bl4[4];
    #pragma unroll
    for (int r=0;r<4;++r){
      int ia = tid + r*256;
      av[r] = *(const float4*)(A + (long)(m0 + (ia>>4))*K + k0 + ((ia&15)<<2));
      int ib = tid + r*256;
      long bo = (long)(n0 + (ib>>3))*K + k0 + ((ib&7)<<3);
      bh4[r] = *(const uint4*)(Bhi + bo);
      bl4[r] = *(const uint4*)(Blo + bo);
    }
    __syncthreads();
    #pragma unroll
    for (int r=0;r<4;++r){
      int ia = tid + r*256;
      int arow = ia>>4, akc = (ia&15)<<2;
      float4 v = av[r];
      unsigned short h0=f2bf(v.x),h1=f2bf(v.y),h2=f2bf(v.z),h3=f2bf(v.w);
      uint2 whi; whi.x = (unsigned)h0 | ((unsigned)h1<<16); whi.y = (unsigned)h2 | ((unsigned)h3<<16);
      *(uint2*)&As_hi[arow][akc] = whi;
      unsigned short l0=f2bf(v.x-bf2f(h0)),l1=f2bf(v.y-bf2f(h1)),
                     l2=f2bf(v.z-bf2f(h2)),l3=f2bf(v.w-bf2f(h3));
      uint2 wlo; wlo.x = (unsigned)l0 | ((unsigned)l1<<16); wlo.y = (unsigned)l2 | ((unsigned)l3<<16);
      *(uint2*)&As_lo[arow][akc] = wlo;
      int ib = tid + r*256;
      int bn = ib>>3, bkc = (ib&7)<<3;
      uint2 t0; t0.x = bh4[r].x; t0.y = bh4[r].y;
      uint2 t1; t1.x = bh4[r].z; t1.y = bh4[r].w;
      *(uint2*)&Bs_hi[bn][bkc]   = t0;
      *(uint2*)&Bs_hi[bn][bkc+4] = t1;
      uint2 t2; t2.x = bl4[r].x; t2.y = bl4[r].y;
      uint2 t3; t3.x = bl4[r].z; t3.y = bl4[r].w;
      *(uint2*)&Bs_lo[bn][bkc]   = t2;
      *(uint2*)&Bs_lo[bn][bkc+4] = t3;
    }
    __syncthreads();
    #pragma unroll
    for (int kk=0; kk<2; ++kk){
      bf16x8_t ah[2], al[2], bh[4], bl[4];
      #pragma unroll
      for (int mf=0; mf<2; ++mf){
        ah[mf] = ldfrag(&As_hi[mw + mf*16 + la][kk*32 + kg]);
        al[mf] = ldfrag(&As_lo[mw + mf*16 + la][kk*32 + kg]);
      }
      #pragma unroll
      for (int nf=0; nf<4; ++nf){
        bh[nf] = ldfrag(&Bs_hi[nw + nf*16 + la][kk*32 + kg]);
        bl[nf] = ldfrag(&Bs_lo[nw + nf*16 + la][kk*32 + kg]);
      }
      #pragma unroll
      for (int mf=0; mf<2; ++mf)
        #pragma unroll
        for (int nf=0; nf<4; ++nf){
          acc[mf][nf] = __builtin_amdgcn_mfma_f32_16x16x32_bf16(ah[mf], bh[nf], acc[mf][nf], 0,0,0);
          acc[mf][nf] = __builtin_amdgcn_mfma_f32_16x16x32_bf16(ah[mf], bl[nf], acc[mf][nf], 0,0,0);
          acc[mf][nf] = __builtin_amdgcn_mfma_f32_16x16x32_bf16(al[mf], bh[nf], acc[mf][nf], 0,0,0);
        }
    }
  }
  // epilogue: C/D layout col=lane&15, row=(lane>>4)*4+reg
  #pragma unroll
  for (int mf=0; mf<2; ++mf){
    int grow0 = m0 + mw + mf*16 + ((lane>>4)<<2);
    #pragma unroll
    for (int nf=0; nf<4; ++nf){
      int gcol = n0 + nw + nf*16 + la;
      float bsv = bias[gcol];
      if (EPI==4){
        float4 o;
        o.x = acc[mf][nf][0] + bsv; o.y = acc[mf][nf][1] + bsv;
        o.z = acc[mf][nf][2] + bsv; o.w = acc[mf][nf][3] + bsv;
        *(float4*)(C + (long)gcol*M + grow0) = o;   // C^T[N][M], contiguous in rows
      } else {
        #pragma unroll
        for (int r=0;r<4;++r){
          int grow = grow0 + r;
          float v = acc[mf][nf][r] + bsv;
          if (EPI==1) v = geluf_(v);
          C[(long)grow*N + gcol] = v;
        }
      }
    }
  }
}

// ---------- terminal GEMM: out = y @ Wo + bo + x ; single-bf16, 64x64 tile ----------
// Terminal output: bf16 quantization error (~3e-3) does not propagate. grid (64,16)=1024 blocks.
__global__ __launch_bounds__(256) void gemm_out_kernel(
    const float* __restrict__ A, const unsigned short* __restrict__ Bhi,
    const float* __restrict__ bias, const float* __restrict__ resid,
    float* __restrict__ C, int M, int N, int K)
{
  __shared__ unsigned short As[64][68];
  __shared__ unsigned short Bs[64][68];
  const int tid = threadIdx.x;
  const int lane = tid & 63, wv = tid >> 6;
  const int wr = wv >> 1, wc = wv & 1;
  const int mw = wr*32, nw = wc*32;
  const int la = lane & 15, kg = (lane >> 4) << 3;
  const int m0 = blockIdx.x * 64, n0 = blockIdx.y * 64;

  f32x4_t acc[2][2];
  #pragma unroll
  for (int i=0;i<2;++i)
    #pragma unroll
    for (int j=0;j<2;++j) acc[i][j] = (f32x4_t){0.f,0.f,0.f,0.f};

  for (int k0 = 0; k0 < K; k0 += 64) {
    float4 av[4]; uint4 b4[2];
    #pragma unroll
    for (int r=0;r<4;++r){
      int ia = tid + r*256;
      av[r] = *(const float4*)(A + (long)(m0 + (ia>>4))*K + k0 + ((ia&15)<<2));
    }
    #pragma unroll
    for (int r=0;r<2;++r){
      int ib = tid + r*256;
      b4[r] = *(const uint4*)(Bhi + (long)(n0 + (ib>>3))*K + k0 + ((ib&7)<<3));
    }
    __syncthreads();
    #pragma unroll
    for (int r=0;r<4;++r){
      int ia = tid + r*256;
      int arow = ia>>4, akc = (ia&15)<<2;
      float4 v = av[r];
      unsigned short h0=f2bf(v.x),h1=f2bf(v.y),h2=f2bf(v.z),h3=f2bf(v.w);
      uint2 w; w.x = (unsigned)h0 | ((unsigned)h1<<16); w.y = (unsigned)h2 | ((unsigned)h3<<16);
      *(uint2*)&As[arow][akc] = w;
    }
    #pragma unroll
    for (int r=0;r<2;++r){
      int ib = tid + r*256;
      int brow = ib>>3, bkc = (ib&7)<<3;
      uint2 t0; t0.x = b4[r].x; t0.y = b4[r].y;
      uint2 t1; t1.x = b4[r].z; t1.y = b4[r].w;
      *(uint2*)&Bs[brow][bkc]   = t0;
      *(uint2*)&Bs[brow][bkc+4] = t1;
    }
    __syncthreads();
    #pragma unroll
    for (int kk=0; kk<2; ++kk){
      bf16x8_t a[2], b[2];
      #pragma unroll
      for (int mf=0; mf<2; ++mf) a[mf] = ldfrag(&As[mw + mf*16 + la][kk*32 + kg]);
      #pragma unroll
      for (int nf=0; nf<2; ++nf) b[nf] = ldfrag(&Bs[nw + nf*16 + la][kk*32 + kg]);
      #pragma unroll
      for (int mf=0; mf<2; ++mf)
        #pragma unroll
        for (int nf=0; nf<2; ++nf)
          acc[mf][nf] = __builtin_amdgcn_mfma_f32_16x16x32_bf16(a[mf], b[nf], acc[mf][nf], 0,0,0);
    }
  }
  #pragma unroll
  for (int mf=0; mf<2; ++mf){
    int grow0 = m0 + mw + mf*16 + ((lane>>4)<<2);
    #pragma unroll
    for (int nf=0; nf<2; ++nf){
      int gcol = n0 + nw + nf*16 + la;
      float bsv = bias[gcol];
      #pragma unroll
      for (int r=0;r<4;++r){
        int grow = grow0 + r;
        C[(long)grow*N + gcol] = acc[mf][nf][r] + bsv + resid[(long)grow*N + gcol];
      }
    }
  }
}

// ---------- real = tanh(a)*cos(2pi*sigmoid(ph)); xn = LN_P(real)*g1+bt1 ----------
__global__ __launch_bounds__(256) void encode_ln_kernel(
    const float* __restrict__ E, const float* __restrict__ g1, const float* __restrict__ bt1,
    float* __restrict__ realp, float* __restrict__ xnp)
{
  int wv = threadIdx.x >> 6, lane = threadIdx.x & 63;
  long row = (long)blockIdx.x*4 + wv;         // 0..4095
  const float* e = E + row*256;
  int p = lane*2;
  float2 a = *(const float2*)(e + p);
  float2 f = *(const float2*)(e + 128 + p);
  const float TWO_PI = 6.28318530717958647692f;
  float r0 = tanhf(a.x) * cosf(TWO_PI * sigmoidf_(f.x));
  float r1 = tanhf(a.y) * cosf(TWO_PI * sigmoidf_(f.y));
  float s = r0+r1, ss = r0*r0 + r1*r1;
  #pragma unroll
  for (int m=1;m<64;m<<=1){ s += __shfl_xor(s,m,64); ss += __shfl_xor(ss,m,64); }
  float mean = s * (1.f/128.f);
  float var  = ss * (1.f/128.f) - mean*mean;
  float inv  = rsqrtf(var + 1e-5f);
  float x0 = (r0-mean)*inv*g1[p]   + bt1[p];
  float x1 = (r1-mean)*inv*g1[p+1] + bt1[p+1];
  *(float2*)(realp + row*128 + p) = make_float2(r0,r1);
  *(float2*)(xnp   + row*128 + p) = make_float2(x0,x1);
}

// ---------- autocorr via MFMA: R(16a+b) = sum_t v[t+16a]*v[t-b], K=544 ----------
// Hankel operands from LDS; 4 shifted copies for aligned B reads; split-bf16 3-MFMA.
// lam=256 edge via VALU. Sigmoid results restaged in LDS, then coalesced float4 stores.
__device__ __forceinline__ int hi_off_(int d){ return d ? (512 + d*1280) : 0; }
__device__ __forceinline__ int lo_off_(int d){ return d ? (1152 + d*1280) : 896; }
__device__ __forceinline__ int physpad_(int m){ return m + ((m >> 6) << 3); }

__global__ __launch_bounds__(256) void autocorr_kernel(
    const float* __restrict__ tT, float* __restrict__ sig)
{
  __shared__ __align__(16) unsigned short pool[4][5632];
  __shared__ float sbuf[4][516];
  const int tid = threadIdx.x;
  const int wv = tid >> 6, lane = tid & 63;
  int bidx = blockIdx.x;                      // 0..2047
  int p4 = bidx & 31; int hb = bidx >> 5; int b = hb & 7, h = hb >> 3;

  // zero-init pool
  unsigned int* pz = (unsigned int*)&pool[0][0];
  for (int i = tid; i < 4*5632/2; i += 256) pz[i] = 0u;
  __syncthreads();

  // stage channel p = p4*4 + wv : logical v[i], copy d at phys(i+16-d)
  unsigned short* P = pool[wv];
  {
    const float* tp = tT + ((long)(h*128 + p4*4 + wv))*4096 + b*512;
    for (int i = lane; i < 512; i += 64) {
      float v = tp[i];
      unsigned short hh = f2bf(v);
      unsigned short ll = f2bf(v - bf2f(hh));
      #pragma unroll
      for (int d = 0; d < 4; ++d) {
        int ph = physpad_(i + 16 - d);
        P[hi_off_(d) + ph] = hh;
        P[lo_off_(d) + ph] = ll;
      }
    }
  }
  __syncthreads();

  const int la = lane & 15, kg8 = (lane >> 4) << 3;
  f32x4_t acc = (f32x4_t){0.f,0.f,0.f,0.f};
  for (int kb = 0; kb < 17; ++kb) {
    int qA = kb*32 + kg8 + la*16 + 16;
    int phA = physpad_(qA);
    bf16x8_t Ah = ldfrag16(P + phA);
    bf16x8_t Al = ldfrag16(P + 896 + phA);
    int qB = kb*32 + kg8 + 16 - la;
    int d = qB & 3;
    int r0 = qB - d, r1 = r0 + 4;
    int ph0 = physpad_(r0), ph1 = physpad_(r1);
    int hio = hi_off_(d), loo = lo_off_(d);
    union { bf16x8_t v; uint2 q[2]; } ub, vb;
    ub.q[0] = *(const uint2*)(P + hio + ph0);
    ub.q[1] = *(const uint2*)(P + hio + ph1);
    vb.q[0] = *(const uint2*)(P + loo + ph0);
    vb.q[1] = *(const uint2*)(P + loo + ph1);
    acc = __builtin_amdgcn_mfma_f32_16x16x32_bf16(Ah, ub.v, acc, 0,0,0);
    acc = __builtin_amdgcn_mfma_f32_16x16x32_bf16(Ah, vb.v, acc, 0,0,0);
    acc = __builtin_amdgcn_mfma_f32_16x16x32_bf16(Al, ub.v, acc, 0,0,0);
  }

  // lag 256 edge: R(256) = sum_{t<256} v[t]v[t+256]
  float r256 = 0.f;
  #pragma unroll
  for (int u = 0; u < 4; ++u) {
    int t = lane*4 + u;
    int p1 = physpad_(t + 16), p2 = physpad_(t + 272);
    float v1 = bf2f(P[p1]) + bf2f(P[896 + p1]);
    float v2 = bf2f(P[p2]) + bf2f(P[896 + p2]);
    r256 = fmaf(v1, v2, r256);
  }
  #pragma unroll
  for (int m = 1; m < 64; m <<= 1) r256 += __shfl_xor(r256, m, 64);

  // restage sigmoid into LDS (C/D layout: col=lane&15 (=b), row=(lane>>4)*4+rr (=a))
  float* SB = sbuf[wv];
  int arow = (lane >> 4) << 2;
  #pragma unroll
  for (int rr = 0; rr < 4; ++rr) {
    int lam = (arow + rr)*16 + la;            // 0..255, each exactly once
    float bv = sigmoidf_(acc[rr]);
    SB[256+lam] = bv;
    if (lam > 0) SB[256-lam] = bv;
  }
  if (lane == 0) SB[0] = sigmoidf_(r256);
  __syncthreads();

  // coalesced store: one float4 (4 channels) per (s)
  float* outp = sig + ((long)(h*4096 + b*512))*128 + p4*4;
  for (int s = tid; s < 512; s += 256) {
    float4 o;
    o.x = sbuf[0][s]; o.y = sbuf[1][s]; o.z = sbuf[2][s]; o.w = sbuf[3][s];
    *(float4*)(outp + (long)s*128) = o;
  }
}

// ---------- gated = real*sig ; y[b,s,h*128+p] = LN_P(gated)*g2+bt2 ----------
__global__ __launch_bounds__(256) void gate_ln_kernel(
    const float* __restrict__ realp, const float* __restrict__ sig,
    const float* __restrict__ g2, const float* __restrict__ bt2,
    float* __restrict__ y)
{
  int wv = threadIdx.x >> 6, lane = threadIdx.x & 63;
  long r = (long)blockIdx.x*4 + wv;           // (h,b,s) row, 0..32767
  int h = (int)(r >> 12);
  long rem = r & 4095;                        // b*512+s
  int p = lane*2;
  float2 rv = *(const float2*)(realp + rem*128 + p);
  float2 sv = *(const float2*)(sig + r*128 + p);
  float a0 = rv.x*sv.x, a1 = rv.y*sv.y;
  float s = a0+a1, ss = a0*a0+a1*a1;
  #pragma unroll
  for (int m=1;m<64;m<<=1){ s += __shfl_xor(s,m,64); ss += __shfl_xor(ss,m,64); }
  float mean = s*(1.f/128.f);
  float var  = ss*(1.f/128.f) - mean*mean;
  float inv  = rsqrtf(var+1e-5f);
  float y0 = (a0-mean)*inv*g2[p]   + bt2[p];
  float y1 = (a1-mean)*inv*g2[p+1] + bt2[p+1];
  *(float2*)(y + rem*1024 + h*128 + p) = make_float2(y0,y1);
}

extern "C" void kernel_launch(void* const* d_in, const int* in_sizes, int n_in,
                              void* d_out, int out_size, void* d_ws, size_t ws_size,
                              hipStream_t stream)
{
  const float* x   = (const float*)d_in[0];
  const float* Wa  = (const float*)d_in[1];
  const float* ba  = (const float*)d_in[2];
  const float* Wp  = (const float*)d_in[3];
  const float* bp  = (const float*)d_in[4];
  const float* g1  = (const float*)d_in[5];
  const float* bt1 = (const float*)d_in[6];
  const float* W1  = (const float*)d_in[7];
  const float* bh1 = (const float*)d_in[8];
  const float* W2  = (const float*)d_in[9];
  const float* bh2 = (const float*)d_in[10];
  const float* g2  = (const float*)d_in[11];
  const float* bt2 = (const float*)d_in[12];
  const float* Wo  = (const float*)d_in[13];
  const float* bo  = (const float*)d_in[14];

  char* p = (char*)d_ws;
  auto alloc = [&](size_t bytes)->char*{ char* r = p; p += (bytes + 255) & ~(size_t)255; return r; };
  float* bcat = (float*)alloc(256*4);
  unsigned short* WcatT_hi = (unsigned short*)alloc(256*1024*2);
  unsigned short* WcatT_lo = (unsigned short*)alloc(256*1024*2);
  unsigned short* W1T_hi   = (unsigned short*)alloc(8*256*128*2);
  unsigned short* W1T_lo   = (unsigned short*)alloc(8*256*128*2);
  unsigned short* W2T_hi   = (unsigned short*)alloc(8*128*256*2);
  unsigned short* W2T_lo   = (unsigned short*)alloc(8*128*256*2);
  unsigned short* WoT_hi   = (unsigned short*)alloc(1024*1024*2);
  unsigned short* WoT_lo   = (unsigned short*)alloc(1024*1024*2);
  float* E     = (float*)alloc((size_t)4096*256*4);
  float* realp = (float*)alloc((size_t)4096*128*4);
  float* xnp   = (float*)alloc((size_t)4096*128*4);
  float* hid   = (float*)alloc((size_t)8*4096*256*4);
  float* tbuf  = (float*)alloc((size_t)8*128*4096*4);   // t^T [h][p][4096]
  float* sigb  = hid;    // hid (32MB) dead after W2-gemm; sig fp32 16MB
  float* ybuf  = tbuf;   // tT dead after autocorr
  float* out   = (float*)d_out;

  bias_pack<<<1,256,0,stream>>>(ba,bp,bcat);
  transpose_split<<<dim3(4,32,1),256,0,stream>>>(Wa, WcatT_hi, WcatT_lo, 1024,128);
  transpose_split<<<dim3(4,32,1),256,0,stream>>>(Wp, WcatT_hi+131072, WcatT_lo+131072, 1024,128);
  transpose_split<<<dim3(8,4,8),256,0,stream>>>(W1, W1T_hi, W1T_lo, 128,256);
  transpose_split<<<dim3(4,8,8),256,0,stream>>>(W2, W2T_hi, W2T_lo, 256,128);
  transpose_split<<<dim3(32,32,1),256,0,stream>>>(Wo, WoT_hi, WoT_lo, 1024,1024);

  // E = x @ [Wa|Wp] + [ba|bp]
  gemm_mfma<0><<<dim3(64,2,1),256,0,stream>>>(x, WcatT_hi, WcatT_lo, bcat, nullptr, E,
                                              4096,256,1024, 0,0,0,0);
  encode_ln_kernel<<<1024,256,0,stream>>>(E,g1,bt1,realp,xnp);
  // hid[h] = gelu(xn @ W1[h] + bh1[h])
  gemm_mfma<1><<<dim3(64,2,8),256,0,stream>>>(xnp, W1T_hi, W1T_lo, bh1, nullptr, hid,
                                              4096,256,128, 0, (long)256*128, 256, (long)4096*256);
  // tT[h] = (hid[h] @ W2[h] + bh2[h])^T  (transposed contiguous store)
  gemm_mfma<4><<<dim3(64,1,8),256,0,stream>>>(hid, W2T_hi, W2T_lo, bh2, nullptr, tbuf,
                                              4096,128,256, (long)4096*256, (long)128*256, 128, (long)128*4096);
  autocorr_kernel<<<2048,256,0,stream>>>(tbuf, sigb);
  gate_ln_kernel<<<8192,256,0,stream>>>(realp, sigb, g2, bt2, ybuf);
  // out = y @ Wo + bo + x   (terminal single-bf16, 64x64 tile, 1024 blocks)
  gemm_out_kernel<<<dim3(64,16,1),256,0,stream>>>(ybuf, WoT_hi, bo, x, out,
                                                  4096,1024,1024);
}